// Round 6
// baseline (557.798 us; speedup 1.0000x reference)
//
#include <hip/hip_runtime.h>

// Problem constants
#define B_   32
#define N_   512
#define C_   768
#define H_   12
#define D_   64
#define HID_ 3072
#define BN_  (B_*N_)      // 16384 rows

typedef unsigned short u16;
typedef __attribute__((ext_vector_type(8))) short  short8;   // 8 bf16 (4 VGPRs)
typedef __attribute__((ext_vector_type(4))) float  float4v;  // 4 fp32 acc
typedef __attribute__((ext_vector_type(4))) float  f4;
typedef __attribute__((ext_vector_type(4))) unsigned short ushort4v;

__device__ __forceinline__ u16 f32_to_bf16(float f) {
  unsigned u = __builtin_bit_cast(unsigned, f);
  u += 0x7fffu + ((u >> 16) & 1u);   // RNE
  return (u16)(u >> 16);
}

// exact-GELU via A&S 7.1.26 erf approx, |err| < 1.5e-7 (below bf16 ulp)
__device__ __forceinline__ float gelu_f(float x) {
  float z = fabsf(x) * 0.70710678118654752f;
  float t = __builtin_amdgcn_rcpf(1.0f + 0.3275911f * z);
  float p = t * (0.254829592f +
            t * (-0.284496736f +
            t * (1.421413741f +
            t * (-1.453152027f +
            t * 1.061405429f))));
  float e = __expf(-z * z);
  float er = 1.0f - p * e;                 // erf(z)
  er = (x < 0.0f) ? -er : er;
  return 0.5f * x * (1.0f + er);
}

// async global->LDS, 16B per lane
__device__ __forceinline__ void load_lds16(const u16* g, u16* l) {
  __builtin_amdgcn_global_load_lds(
      (const __attribute__((address_space(1))) unsigned int*)g,
      (__attribute__((address_space(3))) unsigned int*)l,
      16, 0, 0);
}

// ---------------- merged weight cast f32 -> bf16 (dst buffers contiguous) ----
#define NW0_ (3 * C_ * C_)
#define NW1_ (NW0_ + C_ * C_)
#define NW2_ (NW1_ + HID_ * C_)
#define NW3_ (NW2_ + C_ * HID_)
__global__ __launch_bounds__(256)
void cast4_kernel(const float* __restrict__ s0, const float* __restrict__ s1,
                  const float* __restrict__ s2, const float* __restrict__ s3,
                  u16* __restrict__ dst) {
  int i = blockIdx.x * 256 + threadIdx.x;
  const float* s; int j;
  if (i < NW0_)      { s = s0; j = i; }
  else if (i < NW1_) { s = s1; j = i - NW0_; }
  else if (i < NW2_) { s = s2; j = i - NW1_; }
  else               { s = s3; j = i - NW2_; }
  dst[i] = f32_to_bf16(s[j]);
}

// ---------------- LayerNorm (row = 768 fp32) -> bf16, wave-per-row ----------------
__global__ __launch_bounds__(256)
void ln_kernel(const float* __restrict__ x, const float* __restrict__ w,
               const float* __restrict__ bias, u16* __restrict__ out) {
  const int wave = threadIdx.x >> 6, lane = threadIdx.x & 63;
  const int row  = blockIdx.x * 4 + wave;
  const float* xr = x + (size_t)row * C_;

  f4 v[3];
  float s = 0.f, q = 0.f;
#pragma unroll
  for (int j = 0; j < 3; j++) {
    v[j] = *(const f4*)(xr + j * 256 + lane * 4);
#pragma unroll
    for (int e = 0; e < 4; e++) { s += v[j][e]; q += v[j][e] * v[j][e]; }
  }
#pragma unroll
  for (int off = 1; off < 64; off <<= 1) {
    s += __shfl_xor(s, off);
    q += __shfl_xor(q, off);
  }
  const float mean = s * (1.0f / C_);
  const float var  = q * (1.0f / C_) - mean * mean;
  const float rstd = rsqrtf(var + 1e-5f);

  u16* orow = out + (size_t)row * C_;
#pragma unroll
  for (int j = 0; j < 3; j++) {
    const int c = j * 256 + lane * 4;
    f4 wv = *(const f4*)(w + c);
    f4 bv = *(const f4*)(bias + c);
    ushort4v o;
#pragma unroll
    for (int e = 0; e < 4; e++)
      o[e] = f32_to_bf16((v[j][e] - mean) * rstd * wv[e] + bv[e]);
    *(ushort4v*)(orow + c) = o;   // 8B store
  }
}

// ------- V transpose: qkv unified [BN, 3C] V-cols -> Vt[B*H, D, N] --------------
__global__ __launch_bounds__(256)
void transpose_v(const u16* __restrict__ qkv, u16* __restrict__ vt) {
  __shared__ alignas(16) u16 T[64 * 72];
  const int nt = blockIdx.x, bh = blockIdx.y;
  const int b = bh / H_, h = bh % H_;
  const int tid = threadIdx.x;
  const size_t rs3 = 3 * C_;
  const int r = tid >> 2, dc = (tid & 3) * 16;
  const u16* src = qkv + (size_t)(b * N_ + nt * 64 + r) * rs3 + 2 * C_ + h * D_ + dc;
  short8 a0 = *(const short8*)src;
  short8 a1 = *(const short8*)(src + 8);
#pragma unroll
  for (int j = 0; j < 8; j++) T[(dc + j) * 72 + r] = (u16)a0[j];
#pragma unroll
  for (int j = 0; j < 8; j++) T[(dc + 8 + j) * 72 + r] = (u16)a1[j];
  __syncthreads();
  const int d = tid >> 2, nc = (tid & 3) * 16;
  u16* dst = vt + ((size_t)(b * H_ + h) * D_ + d) * N_ + nt * 64 + nc;
  *(short8*)dst       = *(const short8*)&T[d * 72 + nc];
  *(short8*)(dst + 8) = *(const short8*)&T[d * 72 + nc + 8];
}

// ================= 128x128x(BK=64) bf16 NT GEMM (proven core) ====================
template <int EPI>
__device__ __forceinline__ void gemm_core128(const u16* __restrict__ A, const u16* __restrict__ W,
                                             int N, int K,
                                             const float* __restrict__ bias,
                                             const float* __restrict__ resid,
                                             u16* __restrict__ out_bf, float* __restrict__ out_f) {
  __shared__ alignas(16) u16 As[128 * 64];
  __shared__ alignas(16) u16 Ws[128 * 64];
  const int tid  = threadIdx.x;
  const int wave = tid >> 6;
  const int lane = tid & 63;
  const int quad = lane >> 4;
  const int l15  = lane & 15;

  const int nx    = gridDim.x;
  const int lin   = blockIdx.y * nx + blockIdx.x;
  const int total = nx * gridDim.y;
  const int v     = (lin & 7) * (total >> 3) + (lin >> 3);
  const int m0 = (v / nx) << 7;
  const int n0 = (v % nx) << 7;

  const int wm = (wave >> 1) * 64;
  const int wn = (wave & 1) * 64;

  float4v acc[4][4];
#pragma unroll
  for (int i = 0; i < 4; i++)
#pragma unroll
    for (int j = 0; j < 4; j++) acc[i][j] = (float4v){0.f, 0.f, 0.f, 0.f};

  const int c0   = wave * 4;
  const int srow = lane >> 3;
  const int gcol = ((lane & 7) ^ srow) * 8;
  const u16* Ag[4];
  const u16* Wg[4];
#pragma unroll
  for (int j = 0; j < 4; j++) {
    const int row = (c0 + j) * 8 + srow;
    Ag[j] = A + (size_t)(m0 + row) * K + gcol;
    Wg[j] = W + (size_t)(n0 + row) * K + gcol;
  }

  for (int k0 = 0; k0 < K; k0 += 64) {
    __syncthreads();
#pragma unroll
    for (int j = 0; j < 4; j++) load_lds16(Ag[j] + k0, &As[(c0 + j) * 512]);
#pragma unroll
    for (int j = 0; j < 4; j++) load_lds16(Wg[j] + k0, &Ws[(c0 + j) * 512]);
    __syncthreads();

    short8 af[4][2], bf[4][2];
#pragma unroll
    for (int mi = 0; mi < 4; mi++)
#pragma unroll
      for (int ks = 0; ks < 2; ks++) {
        const int swz = ((ks * 4 + quad) ^ (l15 & 7)) * 8;
        af[mi][ks] = *(const short8*)&As[(wm + mi * 16 + l15) * 64 + swz];
        bf[mi][ks] = *(const short8*)&Ws[(wn + mi * 16 + l15) * 64 + swz];
      }
#pragma unroll
    for (int ks = 0; ks < 2; ks++)
#pragma unroll
      for (int mi = 0; mi < 4; mi++)
#pragma unroll
        for (int ni = 0; ni < 4; ni++)
          acc[mi][ni] = __builtin_amdgcn_mfma_f32_16x16x32_bf16(af[mi][ks], bf[ni][ks], acc[mi][ni], 0, 0, 0);
  }

#pragma unroll
  for (int mi = 0; mi < 4; mi++) {
#pragma unroll
    for (int r = 0; r < 4; r++) {
      const int row = m0 + wm + mi * 16 + quad * 4 + r;
#pragma unroll
      for (int ni = 0; ni < 4; ni++) {
        const int col = n0 + wn + ni * 16 + l15;
        float v2 = acc[mi][ni][r];
        if (EPI == 0) {
          out_bf[(size_t)row * N + col] = f32_to_bf16(v2);
        } else if (EPI == 1) {
          out_bf[(size_t)row * N + col] = f32_to_bf16(gelu_f(v2 + bias[col]));
        } else if (EPI == 2) {
          out_f[(size_t)row * N + col] = 2.0f * (v2 + bias[col]);
        } else {
          out_f[(size_t)row * N + col] = v2 + bias[col] + resid[(size_t)row * N + col];
        }
      }
    }
  }
}

__global__ __launch_bounds__(256, 3)
void gemm_qkv(const u16* __restrict__ A, const u16* __restrict__ W, int N, int K,
              u16* __restrict__ out_bf) {
  gemm_core128<0>(A, W, N, K, nullptr, nullptr, out_bf, nullptr);
}
__global__ __launch_bounds__(256, 3)
void gemm_proj2x(const u16* __restrict__ A, const u16* __restrict__ W, int N, int K,
                 const float* __restrict__ bias, float* __restrict__ out_f) {
  gemm_core128<2>(A, W, N, K, bias, nullptr, nullptr, out_f);
}
__global__ __launch_bounds__(256, 3)
void gemm_fc1gelu(const u16* __restrict__ A, const u16* __restrict__ W, int N, int K,
                  const float* __restrict__ bias, u16* __restrict__ out_bf) {
  gemm_core128<1>(A, W, N, K, bias, nullptr, out_bf, nullptr);
}
__global__ __launch_bounds__(256, 3)
void gemm_fc2res(const u16* __restrict__ A, const u16* __restrict__ W, int N, int K,
                 const float* __restrict__ bias, const float* __restrict__ resid,
                 float* __restrict__ out_f) {
  gemm_core128<3>(A, W, N, K, bias, resid, nullptr, out_f);
}

// ---------------- flash attention v4: barrier-free, K/V direct from L2 ------------
// Round-5 PMC: VALUBusy 47% / MfmaUtil 10% / 16 barriers per block stalled all
// waves in lockstep.  K/V per (b,h) = 128 KB, L2-resident (XCD swizzle keeps the 4
// q-tiles of a bh on one XCD: lin%8 = bh%8).  m169 lesson: staging L2-fit data is
// pure overhead -> drop Ks/Vs staging + BOTH barriers; read K/V fragments directly
// from global like the proven Q path.  LDS = per-wave P buffer only (16 KB).
// Softmax in log2 domain: p = exp2(s*SC - m2), SC = 0.125*log2(e); one fma+exp per
// element (replaces mul+sub+mul chain); p values mathematically identical.
__global__ __launch_bounds__(256)
void attn_kernel(const u16* __restrict__ qkv, const u16* __restrict__ vt,
                 u16* __restrict__ o) {
  __shared__ alignas(16) u16 Ps[8][16 * 64];
  const int tid  = threadIdx.x;
  const int wave = tid >> 6, lane = tid & 63;
  const int quad = lane >> 4, l15 = lane & 15;
  const int lin = blockIdx.x;
  const int bh = lin % 384, qt = lin / 384;
  const int b = bh / H_, h = bh % H_;
  const size_t rs3 = 3 * C_;
  const float SC = 0.125f * 1.44269504088896f;   // 0.125 * log2(e)

  // Q fragments from global (A-layout: m=lane&15, k=quad*8+j), 2 strips
  short8 qf[2][2];
#pragma unroll
  for (int st = 0; st < 2; st++) {
    const int qrow = b * N_ + qt * 128 + st * 64 + wave * 16 + l15;
    const u16* qp = qkv + (size_t)qrow * rs3 + h * D_ + quad * 8;
    qf[st][0] = *(const short8*)qp;
    qf[st][1] = *(const short8*)(qp + 32);
  }

  // K/V per-lane fragment bases (B-layout: n=lane&15 row, k=quad*8 within ks*32)
  const u16* kb = qkv + (size_t)(b * N_ + l15) * rs3 + C_ + h * D_ + quad * 8;
  const u16* vb = vt + ((size_t)bh * D_ + l15) * N_ + quad * 8;

  float m2[2][4], l[2][4];
  float4v oacc[2][4];
#pragma unroll
  for (int st = 0; st < 2; st++)
#pragma unroll
    for (int r = 0; r < 4; r++) { m2[st][r] = -1e30f; l[st][r] = 0.f; }
#pragma unroll
  for (int st = 0; st < 2; st++)
#pragma unroll
    for (int ni = 0; ni < 4; ni++) oacc[st][ni] = (float4v){0.f, 0.f, 0.f, 0.f};

  for (int kt = 0; kt < 8; ++kt) {
    // K fragments direct from global (L2-hit): key = kt*64 + ni*16 + l15
    short8 kf[4][2];
#pragma unroll
    for (int ni = 0; ni < 4; ni++) {
      const u16* kp = kb + (size_t)(kt * 64 + ni * 16) * rs3;
      kf[ni][0] = *(const short8*)kp;
      kf[ni][1] = *(const short8*)(kp + 32);
    }

#pragma unroll
    for (int st = 0; st < 2; st++) {
      u16* myPs = Ps[wave * 2 + st];
      float4v s[4];
#pragma unroll
      for (int ni = 0; ni < 4; ni++) {
        s[ni] = (float4v){0.f, 0.f, 0.f, 0.f};
        s[ni] = __builtin_amdgcn_mfma_f32_16x16x32_bf16(qf[st][0], kf[ni][0], s[ni], 0, 0, 0);
        s[ni] = __builtin_amdgcn_mfma_f32_16x16x32_bf16(qf[st][1], kf[ni][1], s[ni], 0, 0, 0);
      }

      // row-max (raw s units), 16-lane shuffle reduce
      float mt[4];
#pragma unroll
      for (int r = 0; r < 4; r++)
        mt[r] = fmaxf(fmaxf(s[0][r], s[1][r]), fmaxf(s[2][r], s[3][r]));
#pragma unroll
      for (int off = 1; off < 16; off <<= 1)
#pragma unroll
        for (int r = 0; r < 4; r++) mt[r] = fmaxf(mt[r], __shfl_xor(mt[r], off));

      float alpha[4], m2new[4], rsum[4];
#pragma unroll
      for (int r = 0; r < 4; r++) {
        m2new[r] = fmaxf(m2[st][r], mt[r] * SC);
        alpha[r] = exp2f(m2[st][r] - m2new[r]);
        rsum[r] = 0.f;
      }
      // P = exp2(s*SC - m2new); write swizzled: row*64 + ((key>>3)^(row&7))*8 + (key&7)
#pragma unroll
      for (int ni = 0; ni < 4; ni++)
#pragma unroll
        for (int r = 0; r < 4; r++) {
          float p = exp2f(s[ni][r] * SC - m2new[r]);
          rsum[r] += p;
          const int prow = quad * 4 + r;
          const int g = (ni * 2 + (l15 >> 3)) ^ (prow & 7);
          myPs[prow * 64 + g * 8 + (l15 & 7)] = f32_to_bf16(p);
        }
#pragma unroll
      for (int off = 1; off < 16; off <<= 1)
#pragma unroll
        for (int r = 0; r < 4; r++) rsum[r] += __shfl_xor(rsum[r], off);
#pragma unroll
      for (int r = 0; r < 4; r++) { l[st][r] = l[st][r] * alpha[r] + rsum[r]; m2[st][r] = m2new[r]; }
#pragma unroll
      for (int ni = 0; ni < 4; ni++)
#pragma unroll
        for (int r = 0; r < 4; r++) oacc[st][ni][r] *= alpha[r];

      // O += P V  (pf: A[m=q][k=key] from per-wave LDS; vf: B[n=d][k=key] direct)
#pragma unroll
      for (int ks = 0; ks < 2; ks++) {
        const int g = (ks * 4 + quad) ^ (l15 & 7);
        short8 pf = *(const short8*)&myPs[l15 * 64 + g * 8];
#pragma unroll
        for (int ni = 0; ni < 4; ni++) {
          short8 vf = *(const short8*)(vb + (size_t)(ni * 16) * N_ + kt * 64 + ks * 32);
          oacc[st][ni] = __builtin_amdgcn_mfma_f32_16x16x32_bf16(pf, vf, oacc[st][ni], 0, 0, 0);
        }
      }
    }
  }

#pragma unroll
  for (int st = 0; st < 2; st++) {
    float inv[4];
#pragma unroll
    for (int r = 0; r < 4; r++) inv[r] = 1.0f / l[st][r];
#pragma unroll
    for (int ni = 0; ni < 4; ni++)
#pragma unroll
      for (int r = 0; r < 4; r++) {
        int row = b * N_ + qt * 128 + st * 64 + wave * 16 + quad * 4 + r;
        int col = h * D_ + ni * 16 + l15;
        o[(size_t)row * C_ + col] = f32_to_bf16(oacc[st][ni][r] * inv[r]);
      }
  }
}

// ---------------- launch ----------------
extern "C" void kernel_launch(void* const* d_in, const int* in_sizes, int n_in,
                              void* d_out, int out_size, void* d_ws, size_t ws_size,
                              hipStream_t stream) {
  const float* x      = (const float*)d_in[0];
  const float* ln1_w  = (const float*)d_in[1];
  const float* ln1_b  = (const float*)d_in[2];
  const float* qkv_w  = (const float*)d_in[3];
  const float* proj_w = (const float*)d_in[4];
  const float* proj_b = (const float*)d_in[5];
  const float* ln2_w  = (const float*)d_in[6];
  const float* ln2_b  = (const float*)d_in[7];
  const float* fc1_w  = (const float*)d_in[8];
  const float* fc1_b  = (const float*)d_in[9];
  const float* fc2_w  = (const float*)d_in[10];
  const float* fc2_b  = (const float*)d_in[11];
  float* out = (float*)d_out;

  char* ws = (char*)d_ws;
  size_t off = 0;
  auto alloc = [&](size_t bytes) { void* p = ws + off; off += (bytes + 255) & ~255ull; return p; };
  u16* wqkv  = (u16*)alloc((size_t)3 * C_ * C_ * 2);
  u16* wproj = (u16*)alloc((size_t)C_ * C_ * 2);
  u16* wfc1  = (u16*)alloc((size_t)HID_ * C_ * 2);
  u16* wfc2  = (u16*)alloc((size_t)C_ * HID_ * 2);
  u16* wbase = wqkv;   // contiguous (all segment sizes are 256B-multiples)
  u16* regionA = (u16*)alloc((size_t)BN_ * HID_ * 2);  // h | qkv, later o, later act
  float* xnew  = (float*)alloc((size_t)BN_ * C_ * 4);
  u16* h2      = (u16*)alloc((size_t)BN_ * C_ * 2);

  u16* hbuf = regionA;                        // [BN, C]   (dead after QKV)
  u16* qkvb = regionA + (size_t)BN_ * C_;     // [BN, 3C]  (dead after attn)
  u16* obuf = regionA;                        // [BN, C]   overwrites hbuf
  u16* act  = regionA;                        // [BN, HID] overwrites qkv+o
  u16* vtbuf = (u16*)xnew;                    // [B*H, D, N] aliases xnew (dead before proj writes)

  cast4_kernel<<<dim3(NW3_ / 256), 256, 0, stream>>>(qkv_w, proj_w, fc1_w, fc2_w, wbase);

  ln_kernel<<<dim3(BN_ / 4), 256, 0, stream>>>(x, ln1_w, ln1_b, hbuf);

  gemm_qkv<<<dim3(3 * C_ / 128, BN_ / 128), 256, 0, stream>>>(hbuf, wqkv, 3 * C_, C_, qkvb);

  transpose_v<<<dim3(N_ / 64, B_ * H_), 256, 0, stream>>>(qkvb, vtbuf);

  attn_kernel<<<dim3((N_ / 128) * B_ * H_), 256, 0, stream>>>(qkvb, vtbuf, obuf);

  gemm_proj2x<<<dim3(C_ / 128, BN_ / 128), 256, 0, stream>>>(obuf, wproj, C_, C_, proj_b, xnew);

  ln_kernel<<<dim3(BN_ / 4), 256, 0, stream>>>(xnew, ln2_w, ln2_b, h2);

  gemm_fc1gelu<<<dim3(HID_ / 128, BN_ / 128), 256, 0, stream>>>(h2, wfc1, HID_, C_, fc1_b, act);

  gemm_fc2res<<<dim3(C_ / 128, BN_ / 128), 256, 0, stream>>>(act, wfc2, C_, HID_, fc2_b, xnew, out);
}

// Round 7
// 526.329 us; speedup vs baseline: 1.0598x; 1.0598x over previous
//
#include <hip/hip_runtime.h>

// Problem constants
#define B_   32
#define N_   512
#define C_   768
#define H_   12
#define D_   64
#define HID_ 3072
#define BN_  (B_*N_)      // 16384 rows

typedef unsigned short u16;
typedef __attribute__((ext_vector_type(8))) short  short8;   // 8 bf16 (4 VGPRs)
typedef __attribute__((ext_vector_type(4))) float  float4v;  // 4 fp32 acc
typedef __attribute__((ext_vector_type(4))) float  f4;
typedef __attribute__((ext_vector_type(4))) unsigned short ushort4v;

__device__ __forceinline__ u16 f32_to_bf16(float f) {
  unsigned u = __builtin_bit_cast(unsigned, f);
  u += 0x7fffu + ((u >> 16) & 1u);   // RNE
  return (u16)(u >> 16);
}

// exact-GELU via A&S 7.1.26 erf approx, |err| < 1.5e-7 (below bf16 ulp)
__device__ __forceinline__ float gelu_f(float x) {
  float z = fabsf(x) * 0.70710678118654752f;
  float t = __builtin_amdgcn_rcpf(1.0f + 0.3275911f * z);
  float p = t * (0.254829592f +
            t * (-0.284496736f +
            t * (1.421413741f +
            t * (-1.453152027f +
            t * 1.061405429f))));
  float e = __expf(-z * z);
  float er = 1.0f - p * e;                 // erf(z)
  er = (x < 0.0f) ? -er : er;
  return 0.5f * x * (1.0f + er);
}

// async global->LDS, 16B per lane
__device__ __forceinline__ void load_lds16(const u16* g, u16* l) {
  __builtin_amdgcn_global_load_lds(
      (const __attribute__((address_space(1))) unsigned int*)g,
      (__attribute__((address_space(3))) unsigned int*)l,
      16, 0, 0);
}

// ---------------- merged weight cast f32 -> bf16 (dst buffers contiguous) ----
#define NW0_ (3 * C_ * C_)
#define NW1_ (NW0_ + C_ * C_)
#define NW2_ (NW1_ + HID_ * C_)
#define NW3_ (NW2_ + C_ * HID_)
__global__ __launch_bounds__(256)
void cast4_kernel(const float* __restrict__ s0, const float* __restrict__ s1,
                  const float* __restrict__ s2, const float* __restrict__ s3,
                  u16* __restrict__ dst) {
  int i = blockIdx.x * 256 + threadIdx.x;
  const float* s; int j;
  if (i < NW0_)      { s = s0; j = i; }
  else if (i < NW1_) { s = s1; j = i - NW0_; }
  else if (i < NW2_) { s = s2; j = i - NW1_; }
  else               { s = s3; j = i - NW2_; }
  dst[i] = f32_to_bf16(s[j]);
}

// ---------------- LayerNorm (row = 768 fp32) -> bf16, wave-per-row ----------------
__global__ __launch_bounds__(256)
void ln_kernel(const float* __restrict__ x, const float* __restrict__ w,
               const float* __restrict__ bias, u16* __restrict__ out) {
  const int wave = threadIdx.x >> 6, lane = threadIdx.x & 63;
  const int row  = blockIdx.x * 4 + wave;
  const float* xr = x + (size_t)row * C_;

  f4 v[3];
  float s = 0.f, q = 0.f;
#pragma unroll
  for (int j = 0; j < 3; j++) {
    v[j] = *(const f4*)(xr + j * 256 + lane * 4);
#pragma unroll
    for (int e = 0; e < 4; e++) { s += v[j][e]; q += v[j][e] * v[j][e]; }
  }
#pragma unroll
  for (int off = 1; off < 64; off <<= 1) {
    s += __shfl_xor(s, off);
    q += __shfl_xor(q, off);
  }
  const float mean = s * (1.0f / C_);
  const float var  = q * (1.0f / C_) - mean * mean;
  const float rstd = rsqrtf(var + 1e-5f);

  u16* orow = out + (size_t)row * C_;
#pragma unroll
  for (int j = 0; j < 3; j++) {
    const int c = j * 256 + lane * 4;
    f4 wv = *(const f4*)(w + c);
    f4 bv = *(const f4*)(bias + c);
    ushort4v o;
#pragma unroll
    for (int e = 0; e < 4; e++)
      o[e] = f32_to_bf16((v[j][e] - mean) * rstd * wv[e] + bv[e]);
    *(ushort4v*)(orow + c) = o;   // 8B store
  }
}

// ------- V transpose: qkv unified [BN, 3C] V-cols -> Vt[B*H, D, N] --------------
__global__ __launch_bounds__(256)
void transpose_v(const u16* __restrict__ qkv, u16* __restrict__ vt) {
  __shared__ alignas(16) u16 T[64 * 72];
  const int nt = blockIdx.x, bh = blockIdx.y;
  const int b = bh / H_, h = bh % H_;
  const int tid = threadIdx.x;
  const size_t rs3 = 3 * C_;
  const int r = tid >> 2, dc = (tid & 3) * 16;
  const u16* src = qkv + (size_t)(b * N_ + nt * 64 + r) * rs3 + 2 * C_ + h * D_ + dc;
  short8 a0 = *(const short8*)src;
  short8 a1 = *(const short8*)(src + 8);
#pragma unroll
  for (int j = 0; j < 8; j++) T[(dc + j) * 72 + r] = (u16)a0[j];
#pragma unroll
  for (int j = 0; j < 8; j++) T[(dc + 8 + j) * 72 + r] = (u16)a1[j];
  __syncthreads();
  const int d = tid >> 2, nc = (tid & 3) * 16;
  u16* dst = vt + ((size_t)(b * H_ + h) * D_ + d) * N_ + nt * 64 + nc;
  *(short8*)dst       = *(const short8*)&T[d * 72 + nc];
  *(short8*)(dst + 8) = *(const short8*)&T[d * 72 + nc + 8];
}

// ================= 128x128x(BK=64) bf16 NT GEMM (proven core) ====================
template <int EPI>
__device__ __forceinline__ void gemm_core128(const u16* __restrict__ A, const u16* __restrict__ W,
                                             int N, int K,
                                             const float* __restrict__ bias,
                                             const float* __restrict__ resid,
                                             u16* __restrict__ out_bf, float* __restrict__ out_f) {
  __shared__ alignas(16) u16 As[128 * 64];
  __shared__ alignas(16) u16 Ws[128 * 64];
  const int tid  = threadIdx.x;
  const int wave = tid >> 6;
  const int lane = tid & 63;
  const int quad = lane >> 4;
  const int l15  = lane & 15;

  const int nx    = gridDim.x;
  const int lin   = blockIdx.y * nx + blockIdx.x;
  const int total = nx * gridDim.y;
  const int v     = (lin & 7) * (total >> 3) + (lin >> 3);
  const int m0 = (v / nx) << 7;
  const int n0 = (v % nx) << 7;

  const int wm = (wave >> 1) * 64;
  const int wn = (wave & 1) * 64;

  float4v acc[4][4];
#pragma unroll
  for (int i = 0; i < 4; i++)
#pragma unroll
    for (int j = 0; j < 4; j++) acc[i][j] = (float4v){0.f, 0.f, 0.f, 0.f};

  const int c0   = wave * 4;
  const int srow = lane >> 3;
  const int gcol = ((lane & 7) ^ srow) * 8;
  const u16* Ag[4];
  const u16* Wg[4];
#pragma unroll
  for (int j = 0; j < 4; j++) {
    const int row = (c0 + j) * 8 + srow;
    Ag[j] = A + (size_t)(m0 + row) * K + gcol;
    Wg[j] = W + (size_t)(n0 + row) * K + gcol;
  }

  for (int k0 = 0; k0 < K; k0 += 64) {
    __syncthreads();
#pragma unroll
    for (int j = 0; j < 4; j++) load_lds16(Ag[j] + k0, &As[(c0 + j) * 512]);
#pragma unroll
    for (int j = 0; j < 4; j++) load_lds16(Wg[j] + k0, &Ws[(c0 + j) * 512]);
    __syncthreads();

    short8 af[4][2], bf[4][2];
#pragma unroll
    for (int mi = 0; mi < 4; mi++)
#pragma unroll
      for (int ks = 0; ks < 2; ks++) {
        const int swz = ((ks * 4 + quad) ^ (l15 & 7)) * 8;
        af[mi][ks] = *(const short8*)&As[(wm + mi * 16 + l15) * 64 + swz];
        bf[mi][ks] = *(const short8*)&Ws[(wn + mi * 16 + l15) * 64 + swz];
      }
#pragma unroll
    for (int ks = 0; ks < 2; ks++)
#pragma unroll
      for (int mi = 0; mi < 4; mi++)
#pragma unroll
        for (int ni = 0; ni < 4; ni++)
          acc[mi][ni] = __builtin_amdgcn_mfma_f32_16x16x32_bf16(af[mi][ks], bf[ni][ks], acc[mi][ni], 0, 0, 0);
  }

#pragma unroll
  for (int mi = 0; mi < 4; mi++) {
#pragma unroll
    for (int r = 0; r < 4; r++) {
      const int row = m0 + wm + mi * 16 + quad * 4 + r;
#pragma unroll
      for (int ni = 0; ni < 4; ni++) {
        const int col = n0 + wn + ni * 16 + l15;
        float v2 = acc[mi][ni][r];
        if (EPI == 0) {
          out_bf[(size_t)row * N + col] = f32_to_bf16(v2);
        } else if (EPI == 1) {
          out_bf[(size_t)row * N + col] = f32_to_bf16(gelu_f(v2 + bias[col]));
        } else if (EPI == 2) {
          out_f[(size_t)row * N + col] = 2.0f * (v2 + bias[col]);
        } else {
          out_f[(size_t)row * N + col] = v2 + bias[col] + resid[(size_t)row * N + col];
        }
      }
    }
  }
}

__global__ __launch_bounds__(256, 3)
void gemm_qkv(const u16* __restrict__ A, const u16* __restrict__ W, int N, int K,
              u16* __restrict__ out_bf) {
  gemm_core128<0>(A, W, N, K, nullptr, nullptr, out_bf, nullptr);
}
__global__ __launch_bounds__(256, 3)
void gemm_proj2x(const u16* __restrict__ A, const u16* __restrict__ W, int N, int K,
                 const float* __restrict__ bias, float* __restrict__ out_f) {
  gemm_core128<2>(A, W, N, K, bias, nullptr, nullptr, out_f);
}
__global__ __launch_bounds__(256, 3)
void gemm_fc1gelu(const u16* __restrict__ A, const u16* __restrict__ W, int N, int K,
                  const float* __restrict__ bias, u16* __restrict__ out_bf) {
  gemm_core128<1>(A, W, N, K, bias, nullptr, out_bf, nullptr);
}
__global__ __launch_bounds__(256, 3)
void gemm_fc2res(const u16* __restrict__ A, const u16* __restrict__ W, int N, int K,
                 const float* __restrict__ bias, const float* __restrict__ resid,
                 float* __restrict__ out_f) {
  gemm_core128<3>(A, W, N, K, bias, resid, nullptr, out_f);
}

// ---------------- flash attention v5: LDS-staged (coalesced), 2-phase dbuf --------
// Round-6 lesson: direct K/V reads are 4.6KB-stride gathers (64 cache lines/wave)
// -> L1-request-bound, 160us.  Staging via global_load_lds IS the coalescer.
// v5 = round-5 staged structure + catalog 2-phase recipe: double-buffer Ks/Vs,
// issue tile kt+1's stage at TOP of iter kt (latency hides under ~2500cyc compute),
// ONE __syncthreads per tile (its vmcnt0-drain is cheap: loads done under compute).
// m97 asm evidence: compiler drains vmcnt only AT barriers, not before ds_reads.
// + log2-domain softmax (r6-verified), defer-max T13 (exact), setprio T5.
__global__ __launch_bounds__(256)
void attn_kernel(const u16* __restrict__ qkv, const u16* __restrict__ vt,
                 u16* __restrict__ o) {
  __shared__ alignas(16) u16 Ks[2][64 * 64];
  __shared__ alignas(16) u16 Vs[2][64 * 64];
  __shared__ alignas(16) u16 Ps[8][16 * 64];
  const int tid  = threadIdx.x;
  const int wave = tid >> 6, lane = tid & 63;
  const int quad = lane >> 4, l15 = lane & 15;
  const int lin = blockIdx.x;
  const int bh = lin % 384, qt = lin / 384;
  const int b = bh / H_, h = bh % H_;
  const size_t rs3 = 3 * C_;
  const float SC = 0.125f * 1.44269504088896f;   // 0.125 * log2(e)

  // Q fragments from global (A-layout: m=lane&15, k=quad*8+j), 2 strips
  short8 qf[2][2];
#pragma unroll
  for (int st = 0; st < 2; st++) {
    const int qrow = b * N_ + qt * 128 + st * 64 + wave * 16 + l15;
    const u16* qp = qkv + (size_t)qrow * rs3 + h * D_ + quad * 8;
    qf[st][0] = *(const short8*)qp;
    qf[st][1] = *(const short8*)(qp + 32);
  }

  // staging sources (8 chunks of 8 rows; wave stages chunks 2w, 2w+1)
  const int srow = lane >> 3;
  const int gcol = ((lane & 7) ^ srow) * 8;
  const int ch0 = wave * 2, ch1 = wave * 2 + 1;
  const u16* kg0 = qkv + (size_t)(b * N_ + ch0 * 8 + srow) * rs3 + C_ + h * D_ + gcol;
  const u16* kg1 = qkv + (size_t)(b * N_ + ch1 * 8 + srow) * rs3 + C_ + h * D_ + gcol;
  const u16* vg0 = vt + ((size_t)bh * D_ + ch0 * 8 + srow) * N_ + gcol;
  const u16* vg1 = vt + ((size_t)bh * D_ + ch1 * 8 + srow) * N_ + gcol;

  float m2[2][4], l[2][4];
  float4v oacc[2][4];
#pragma unroll
  for (int st = 0; st < 2; st++)
#pragma unroll
    for (int r = 0; r < 4; r++) { m2[st][r] = -1e30f; l[st][r] = 0.f; }
#pragma unroll
  for (int st = 0; st < 2; st++)
#pragma unroll
    for (int ni = 0; ni < 4; ni++) oacc[st][ni] = (float4v){0.f, 0.f, 0.f, 0.f};

  // prologue: stage tile 0 -> buf 0
  load_lds16(kg0, &Ks[0][ch0 * 512]);
  load_lds16(kg1, &Ks[0][ch1 * 512]);
  load_lds16(vg0, &Vs[0][ch0 * 512]);
  load_lds16(vg1, &Vs[0][ch1 * 512]);
  __syncthreads();

  for (int kt = 0; kt < 8; ++kt) {
    const int buf = kt & 1;
    // issue next tile's stage FIRST (latency hides under this tile's compute)
    if (kt < 7) {
      load_lds16(kg0 + (size_t)((kt + 1) * 64) * rs3, &Ks[buf ^ 1][ch0 * 512]);
      load_lds16(kg1 + (size_t)((kt + 1) * 64) * rs3, &Ks[buf ^ 1][ch1 * 512]);
      load_lds16(vg0 + (kt + 1) * 64, &Vs[buf ^ 1][ch0 * 512]);
      load_lds16(vg1 + (kt + 1) * 64, &Vs[buf ^ 1][ch1 * 512]);
    }

    // K fragments (B[n=key][k=d]) shared by both strips
    short8 kf[4][2];
#pragma unroll
    for (int ni = 0; ni < 4; ni++)
#pragma unroll
      for (int ks = 0; ks < 2; ks++)
        kf[ni][ks] = *(const short8*)&Ks[buf][(ni * 16 + l15) * 64 + ((ks * 4 + quad) ^ (l15 & 7)) * 8];

#pragma unroll
    for (int st = 0; st < 2; st++) {
      u16* myPs = Ps[wave * 2 + st];
      float4v s[4];
      __builtin_amdgcn_s_setprio(1);
#pragma unroll
      for (int ni = 0; ni < 4; ni++) {
        s[ni] = (float4v){0.f, 0.f, 0.f, 0.f};
        s[ni] = __builtin_amdgcn_mfma_f32_16x16x32_bf16(qf[st][0], kf[ni][0], s[ni], 0, 0, 0);
        s[ni] = __builtin_amdgcn_mfma_f32_16x16x32_bf16(qf[st][1], kf[ni][1], s[ni], 0, 0, 0);
      }
      __builtin_amdgcn_s_setprio(0);

      // row-max (raw units), 16-lane shuffle reduce
      float mt[4];
#pragma unroll
      for (int r = 0; r < 4; r++)
        mt[r] = fmaxf(fmaxf(s[0][r], s[1][r]), fmaxf(s[2][r], s[3][r]));
#pragma unroll
      for (int off = 1; off < 16; off <<= 1)
#pragma unroll
        for (int r = 0; r < 4; r++) mt[r] = fmaxf(mt[r], __shfl_xor(mt[r], off));

      // defer-max (T13, exact): only rescale when max grew past THR (log2 units)
      float g = -1e30f;
#pragma unroll
      for (int r = 0; r < 4; r++) g = fmaxf(g, mt[r] * SC - m2[st][r]);
      if (!__all(g <= 8.0f)) {
#pragma unroll
        for (int r = 0; r < 4; r++) {
          float m2n = fmaxf(m2[st][r], mt[r] * SC);
          float alpha = exp2f(m2[st][r] - m2n);
          m2[st][r] = m2n;
          l[st][r] *= alpha;
#pragma unroll
          for (int ni = 0; ni < 4; ni++) oacc[st][ni][r] *= alpha;
        }
      }

      // P = exp2(s*SC - m2); write swizzled: row*64 + ((key>>3)^(row&7))*8 + (key&7)
      float rsum[4] = {0.f, 0.f, 0.f, 0.f};
#pragma unroll
      for (int ni = 0; ni < 4; ni++)
#pragma unroll
        for (int r = 0; r < 4; r++) {
          float p = exp2f(s[ni][r] * SC - m2[st][r]);
          rsum[r] += p;
          const int prow = quad * 4 + r;
          const int gsw = (ni * 2 + (l15 >> 3)) ^ (prow & 7);
          myPs[prow * 64 + gsw * 8 + (l15 & 7)] = f32_to_bf16(p);
        }
#pragma unroll
      for (int off = 1; off < 16; off <<= 1)
#pragma unroll
        for (int r = 0; r < 4; r++) rsum[r] += __shfl_xor(rsum[r], off);
#pragma unroll
      for (int r = 0; r < 4; r++) l[st][r] += rsum[r];

      // O += P V  (pf: A[m=q][k=key]; vf: B[n=d][k=key] from Vs[buf], swizzled)
      __builtin_amdgcn_s_setprio(1);
#pragma unroll
      for (int ks = 0; ks < 2; ks++) {
        const int gsw = (ks * 4 + quad) ^ (l15 & 7);
        short8 pf = *(const short8*)&myPs[l15 * 64 + gsw * 8];
#pragma unroll
        for (int ni = 0; ni < 4; ni++) {
          short8 vf = *(const short8*)&Vs[buf][(ni * 16 + l15) * 64 + ((ks * 4 + quad) ^ (l15 & 7)) * 8];
          oacc[st][ni] = __builtin_amdgcn_mfma_f32_16x16x32_bf16(pf, vf, oacc[st][ni], 0, 0, 0);
        }
      }
      __builtin_amdgcn_s_setprio(0);
    }

    __syncthreads();   // drains kt+1 staging (already done) + joins before overwrite
  }

#pragma unroll
  for (int st = 0; st < 2; st++) {
    float inv[4];
#pragma unroll
    for (int r = 0; r < 4; r++) inv[r] = 1.0f / l[st][r];
#pragma unroll
    for (int ni = 0; ni < 4; ni++)
#pragma unroll
      for (int r = 0; r < 4; r++) {
        int row = b * N_ + qt * 128 + st * 64 + wave * 16 + quad * 4 + r;
        int col = h * D_ + ni * 16 + l15;
        o[(size_t)row * C_ + col] = f32_to_bf16(oacc[st][ni][r] * inv[r]);
      }
  }
}

// ---------------- launch ----------------
extern "C" void kernel_launch(void* const* d_in, const int* in_sizes, int n_in,
                              void* d_out, int out_size, void* d_ws, size_t ws_size,
                              hipStream_t stream) {
  const float* x      = (const float*)d_in[0];
  const float* ln1_w  = (const float*)d_in[1];
  const float* ln1_b  = (const float*)d_in[2];
  const float* qkv_w  = (const float*)d_in[3];
  const float* proj_w = (const float*)d_in[4];
  const float* proj_b = (const float*)d_in[5];
  const float* ln2_w  = (const float*)d_in[6];
  const float* ln2_b  = (const float*)d_in[7];
  const float* fc1_w  = (const float*)d_in[8];
  const float* fc1_b  = (const float*)d_in[9];
  const float* fc2_w  = (const float*)d_in[10];
  const float* fc2_b  = (const float*)d_in[11];
  float* out = (float*)d_out;

  char* ws = (char*)d_ws;
  size_t off = 0;
  auto alloc = [&](size_t bytes) { void* p = ws + off; off += (bytes + 255) & ~255ull; return p; };
  u16* wqkv  = (u16*)alloc((size_t)3 * C_ * C_ * 2);
  u16* wproj = (u16*)alloc((size_t)C_ * C_ * 2);
  u16* wfc1  = (u16*)alloc((size_t)HID_ * C_ * 2);
  u16* wfc2  = (u16*)alloc((size_t)C_ * HID_ * 2);
  u16* wbase = wqkv;   // contiguous (all segment sizes are 256B-multiples)
  u16* regionA = (u16*)alloc((size_t)BN_ * HID_ * 2);  // h | qkv, later o, later act
  float* xnew  = (float*)alloc((size_t)BN_ * C_ * 4);
  u16* h2      = (u16*)alloc((size_t)BN_ * C_ * 2);

  u16* hbuf = regionA;                        // [BN, C]   (dead after QKV)
  u16* qkvb = regionA + (size_t)BN_ * C_;     // [BN, 3C]  (dead after attn)
  u16* obuf = regionA;                        // [BN, C]   overwrites hbuf
  u16* act  = regionA;                        // [BN, HID] overwrites qkv+o
  u16* vtbuf = (u16*)xnew;                    // [B*H, D, N] aliases xnew (dead before proj writes)

  cast4_kernel<<<dim3(NW3_ / 256), 256, 0, stream>>>(qkv_w, proj_w, fc1_w, fc2_w, wbase);

  ln_kernel<<<dim3(BN_ / 4), 256, 0, stream>>>(x, ln1_w, ln1_b, hbuf);

  gemm_qkv<<<dim3(3 * C_ / 128, BN_ / 128), 256, 0, stream>>>(hbuf, wqkv, 3 * C_, C_, qkvb);

  transpose_v<<<dim3(N_ / 64, B_ * H_), 256, 0, stream>>>(qkvb, vtbuf);

  attn_kernel<<<dim3((N_ / 128) * B_ * H_), 256, 0, stream>>>(qkvb, vtbuf, obuf);

  gemm_proj2x<<<dim3(C_ / 128, BN_ / 128), 256, 0, stream>>>(obuf, wproj, C_, C_, proj_b, xnew);

  ln_kernel<<<dim3(BN_ / 4), 256, 0, stream>>>(xnew, ln2_w, ln2_b, h2);

  gemm_fc1gelu<<<dim3(HID_ / 128, BN_ / 128), 256, 0, stream>>>(h2, wfc1, HID_, C_, fc1_b, act);

  gemm_fc2res<<<dim3(C_ / 128, BN_ / 128), 256, 0, stream>>>(act, wfc2, C_, HID_, fc2_b, xnew, out);
}

// Round 9
// 520.477 us; speedup vs baseline: 1.0717x; 1.0112x over previous
//
#include <hip/hip_runtime.h>

// Problem constants
#define B_   32
#define N_   512
#define C_   768
#define H_   12
#define D_   64
#define HID_ 3072
#define BN_  (B_*N_)      // 16384 rows

typedef unsigned short u16;
typedef __attribute__((ext_vector_type(8))) short  short8;   // 8 bf16 (4 VGPRs)
typedef __attribute__((ext_vector_type(4))) float  float4v;  // 4 fp32 acc
typedef __attribute__((ext_vector_type(4))) float  f4;
typedef __attribute__((ext_vector_type(4))) unsigned short ushort4v;

__device__ __forceinline__ u16 f32_to_bf16(float f) {
  unsigned u = __builtin_bit_cast(unsigned, f);
  u += 0x7fffu + ((u >> 16) & 1u);   // RNE
  return (u16)(u >> 16);
}

// exact-GELU via A&S 7.1.26 erf approx, |err| < 1.5e-7 (below bf16 ulp)
__device__ __forceinline__ float gelu_f(float x) {
  float z = fabsf(x) * 0.70710678118654752f;
  float t = __builtin_amdgcn_rcpf(1.0f + 0.3275911f * z);
  float p = t * (0.254829592f +
            t * (-0.284496736f +
            t * (1.421413741f +
            t * (-1.453152027f +
            t * 1.061405429f))));
  float e = __expf(-z * z);
  float er = 1.0f - p * e;                 // erf(z)
  er = (x < 0.0f) ? -er : er;
  return 0.5f * x * (1.0f + er);
}

// async global->LDS, 16B per lane
__device__ __forceinline__ void load_lds16(const u16* g, u16* l) {
  __builtin_amdgcn_global_load_lds(
      (const __attribute__((address_space(1))) unsigned int*)g,
      (__attribute__((address_space(3))) unsigned int*)l,
      16, 0, 0);
}

// ---------------- merged weight cast f32 -> bf16 (dst buffers contiguous) ----
#define NW0_ (3 * C_ * C_)
#define NW1_ (NW0_ + C_ * C_)
#define NW2_ (NW1_ + HID_ * C_)
#define NW3_ (NW2_ + C_ * HID_)
__global__ __launch_bounds__(256)
void cast4_kernel(const float* __restrict__ s0, const float* __restrict__ s1,
                  const float* __restrict__ s2, const float* __restrict__ s3,
                  u16* __restrict__ dst) {
  int i = blockIdx.x * 256 + threadIdx.x;
  const float* s; int j;
  if (i < NW0_)      { s = s0; j = i; }
  else if (i < NW1_) { s = s1; j = i - NW0_; }
  else if (i < NW2_) { s = s2; j = i - NW1_; }
  else               { s = s3; j = i - NW2_; }
  dst[i] = f32_to_bf16(s[j]);
}

// ---------------- LayerNorm (row = 768 fp32) -> bf16, wave-per-row ----------------
__global__ __launch_bounds__(256)
void ln_kernel(const float* __restrict__ x, const float* __restrict__ w,
               const float* __restrict__ bias, u16* __restrict__ out) {
  const int wave = threadIdx.x >> 6, lane = threadIdx.x & 63;
  const int row  = blockIdx.x * 4 + wave;
  const float* xr = x + (size_t)row * C_;

  f4 v[3];
  float s = 0.f, q = 0.f;
#pragma unroll
  for (int j = 0; j < 3; j++) {
    v[j] = *(const f4*)(xr + j * 256 + lane * 4);
#pragma unroll
    for (int e = 0; e < 4; e++) { s += v[j][e]; q += v[j][e] * v[j][e]; }
  }
#pragma unroll
  for (int off = 1; off < 64; off <<= 1) {
    s += __shfl_xor(s, off);
    q += __shfl_xor(q, off);
  }
  const float mean = s * (1.0f / C_);
  const float var  = q * (1.0f / C_) - mean * mean;
  const float rstd = rsqrtf(var + 1e-5f);

  u16* orow = out + (size_t)row * C_;
#pragma unroll
  for (int j = 0; j < 3; j++) {
    const int c = j * 256 + lane * 4;
    f4 wv = *(const f4*)(w + c);
    f4 bv = *(const f4*)(bias + c);
    ushort4v o;
#pragma unroll
    for (int e = 0; e < 4; e++)
      o[e] = f32_to_bf16((v[j][e] - mean) * rstd * wv[e] + bv[e]);
    *(ushort4v*)(orow + c) = o;   // 8B store
  }
}

// ------- V transpose: qkv unified [BN, 3C] V-cols -> Vt[B*H, D, N] --------------
__global__ __launch_bounds__(256)
void transpose_v(const u16* __restrict__ qkv, u16* __restrict__ vt) {
  __shared__ alignas(16) u16 T[64 * 72];
  const int nt = blockIdx.x, bh = blockIdx.y;
  const int b = bh / H_, h = bh % H_;
  const int tid = threadIdx.x;
  const size_t rs3 = 3 * C_;
  const int r = tid >> 2, dc = (tid & 3) * 16;
  const u16* src = qkv + (size_t)(b * N_ + nt * 64 + r) * rs3 + 2 * C_ + h * D_ + dc;
  short8 a0 = *(const short8*)src;
  short8 a1 = *(const short8*)(src + 8);
#pragma unroll
  for (int j = 0; j < 8; j++) T[(dc + j) * 72 + r] = (u16)a0[j];
#pragma unroll
  for (int j = 0; j < 8; j++) T[(dc + 8 + j) * 72 + r] = (u16)a1[j];
  __syncthreads();
  const int d = tid >> 2, nc = (tid & 3) * 16;
  u16* dst = vt + ((size_t)(b * H_ + h) * D_ + d) * N_ + nt * 64 + nc;
  *(short8*)dst       = *(const short8*)&T[d * 72 + nc];
  *(short8*)(dst + 8) = *(const short8*)&T[d * 72 + nc + 8];
}

// ================= 128x128x(BK=64) bf16 NT GEMM (proven core) ====================
template <int EPI>
__device__ __forceinline__ void gemm_core128(const u16* __restrict__ A, const u16* __restrict__ W,
                                             int N, int K,
                                             const float* __restrict__ bias,
                                             const float* __restrict__ resid,
                                             u16* __restrict__ out_bf, float* __restrict__ out_f) {
  __shared__ alignas(16) u16 As[128 * 64];
  __shared__ alignas(16) u16 Ws[128 * 64];
  const int tid  = threadIdx.x;
  const int wave = tid >> 6;
  const int lane = tid & 63;
  const int quad = lane >> 4;
  const int l15  = lane & 15;

  const int nx    = gridDim.x;
  const int lin   = blockIdx.y * nx + blockIdx.x;
  const int total = nx * gridDim.y;
  const int v     = (lin & 7) * (total >> 3) + (lin >> 3);
  const int m0 = (v / nx) << 7;
  const int n0 = (v % nx) << 7;

  const int wm = (wave >> 1) * 64;
  const int wn = (wave & 1) * 64;

  float4v acc[4][4];
#pragma unroll
  for (int i = 0; i < 4; i++)
#pragma unroll
    for (int j = 0; j < 4; j++) acc[i][j] = (float4v){0.f, 0.f, 0.f, 0.f};

  const int c0   = wave * 4;
  const int srow = lane >> 3;
  const int gcol = ((lane & 7) ^ srow) * 8;
  const u16* Ag[4];
  const u16* Wg[4];
#pragma unroll
  for (int j = 0; j < 4; j++) {
    const int row = (c0 + j) * 8 + srow;
    Ag[j] = A + (size_t)(m0 + row) * K + gcol;
    Wg[j] = W + (size_t)(n0 + row) * K + gcol;
  }

  for (int k0 = 0; k0 < K; k0 += 64) {
    __syncthreads();
#pragma unroll
    for (int j = 0; j < 4; j++) load_lds16(Ag[j] + k0, &As[(c0 + j) * 512]);
#pragma unroll
    for (int j = 0; j < 4; j++) load_lds16(Wg[j] + k0, &Ws[(c0 + j) * 512]);
    __syncthreads();

    short8 af[4][2], bf[4][2];
#pragma unroll
    for (int mi = 0; mi < 4; mi++)
#pragma unroll
      for (int ks = 0; ks < 2; ks++) {
        const int swz = ((ks * 4 + quad) ^ (l15 & 7)) * 8;
        af[mi][ks] = *(const short8*)&As[(wm + mi * 16 + l15) * 64 + swz];
        bf[mi][ks] = *(const short8*)&Ws[(wn + mi * 16 + l15) * 64 + swz];
      }
#pragma unroll
    for (int ks = 0; ks < 2; ks++)
#pragma unroll
      for (int mi = 0; mi < 4; mi++)
#pragma unroll
        for (int ni = 0; ni < 4; ni++)
          acc[mi][ni] = __builtin_amdgcn_mfma_f32_16x16x32_bf16(af[mi][ks], bf[ni][ks], acc[mi][ni], 0, 0, 0);
  }

#pragma unroll
  for (int mi = 0; mi < 4; mi++) {
#pragma unroll
    for (int r = 0; r < 4; r++) {
      const int row = m0 + wm + mi * 16 + quad * 4 + r;
#pragma unroll
      for (int ni = 0; ni < 4; ni++) {
        const int col = n0 + wn + ni * 16 + l15;
        float v2 = acc[mi][ni][r];
        if (EPI == 0) {
          out_bf[(size_t)row * N + col] = f32_to_bf16(v2);
        } else if (EPI == 1) {
          out_bf[(size_t)row * N + col] = f32_to_bf16(gelu_f(v2 + bias[col]));
        } else if (EPI == 2) {
          out_f[(size_t)row * N + col] = 2.0f * (v2 + bias[col]);
        } else {
          out_f[(size_t)row * N + col] = v2 + bias[col] + resid[(size_t)row * N + col];
        }
      }
    }
  }
}

__global__ __launch_bounds__(256, 3)
void gemm_qkv(const u16* __restrict__ A, const u16* __restrict__ W, int N, int K,
              u16* __restrict__ out_bf) {
  gemm_core128<0>(A, W, N, K, nullptr, nullptr, out_bf, nullptr);
}
__global__ __launch_bounds__(256, 3)
void gemm_proj2x(const u16* __restrict__ A, const u16* __restrict__ W, int N, int K,
                 const float* __restrict__ bias, float* __restrict__ out_f) {
  gemm_core128<2>(A, W, N, K, bias, nullptr, nullptr, out_f);
}
__global__ __launch_bounds__(256, 3)
void gemm_fc1gelu(const u16* __restrict__ A, const u16* __restrict__ W, int N, int K,
                  const float* __restrict__ bias, u16* __restrict__ out_bf) {
  gemm_core128<1>(A, W, N, K, bias, nullptr, out_bf, nullptr);
}
__global__ __launch_bounds__(256, 3)
void gemm_fc2res(const u16* __restrict__ A, const u16* __restrict__ W, int N, int K,
                 const float* __restrict__ bias, const float* __restrict__ resid,
                 float* __restrict__ out_f) {
  gemm_core128<3>(A, W, N, K, bias, resid, nullptr, out_f);
}

// ---------------- flash attention v6: 2-wave blocks, 8 blocks/CU ------------------
// r7 A/B: LDS 32K->48K cut 4->3 blocks/CU and cost +19% despite fewer barriers ->
// blocks/CU is the dominant lever (latency-bound kernel; m114 implicit overlap).
// v6: 128-thread blocks, LDS = 20 KB -> 8 blocks/CU (16 waves = VGPR cap).
// Single-buffer 2-barrier loop (r5-proven); cross-block TLP hides stage latency.
// Keeps r6/r7-verified numerics: log2 softmax, exact defer-max, setprio.
// Grid 3072 = 8 qt x 384 bh (384%8==0 keeps blocks of one bh on one XCD).
__global__ __launch_bounds__(128)
void attn_kernel(const u16* __restrict__ qkv, const u16* __restrict__ vt,
                 u16* __restrict__ o) {
  __shared__ alignas(16) u16 Ks[64 * 64];
  __shared__ alignas(16) u16 Vs[64 * 64];
  __shared__ alignas(16) u16 Ps[2][16 * 64];
  const int tid  = threadIdx.x;
  const int wave = tid >> 6, lane = tid & 63;
  const int quad = lane >> 4, l15 = lane & 15;
  const int lin = blockIdx.x;
  const int bh = lin % 384, qt = lin / 384;      // qt in 0..7 (64 q-rows each)
  const int b = bh / H_, h = bh % H_;
  const size_t rs3 = 3 * C_;
  const float SC = 0.125f * 1.44269504088896f;   // 0.125 * log2(e)

  // Q fragments (A-layout: m=lane&15, k=quad*8+j), 2 strips of 16 q per wave
  short8 qf[2][2];
#pragma unroll
  for (int st = 0; st < 2; st++) {
    const int qrow = b * N_ + qt * 64 + st * 32 + wave * 16 + l15;
    const u16* qp = qkv + (size_t)qrow * rs3 + h * D_ + quad * 8;
    qf[st][0] = *(const short8*)qp;
    qf[st][1] = *(const short8*)(qp + 32);
  }

  // staging sources: 8 chunks of 8 rows each for K and V; wave stages 4 of each.
  const int srow = lane >> 3;
  const int gcol = ((lane & 7) ^ srow) * 8;
  const u16* kg = qkv + (size_t)(b * N_ + wave * 32 + srow) * rs3 + C_ + h * D_ + gcol;
  const u16* vg = vt + ((size_t)bh * D_ + wave * 32 + srow) * N_ + gcol;

  float m2[2][4], l[2][4];
  float4v oacc[2][4];
#pragma unroll
  for (int st = 0; st < 2; st++)
#pragma unroll
    for (int r = 0; r < 4; r++) { m2[st][r] = -1e30f; l[st][r] = 0.f; }
#pragma unroll
  for (int st = 0; st < 2; st++)
#pragma unroll
    for (int ni = 0; ni < 4; ni++) oacc[st][ni] = (float4v){0.f, 0.f, 0.f, 0.f};

  for (int kt = 0; kt < 8; ++kt) {
    __syncthreads();
#pragma unroll
    for (int j = 0; j < 4; j++) {
      load_lds16(kg + (size_t)(kt * 64 + j * 8) * rs3, &Ks[(wave * 4 + j) * 512]);
      load_lds16(vg + (size_t)(j * 8) * N_ + kt * 64,  &Vs[(wave * 4 + j) * 512]);
    }
    __syncthreads();

    // K fragments (B[n=key][k=d]) shared by both strips
    short8 kf[4][2];
#pragma unroll
    for (int ni = 0; ni < 4; ni++)
#pragma unroll
      for (int ks = 0; ks < 2; ks++)
        kf[ni][ks] = *(const short8*)&Ks[(ni * 16 + l15) * 64 + ((ks * 4 + quad) ^ (l15 & 7)) * 8];

#pragma unroll
    for (int st = 0; st < 2; st++) {
      u16* myPs = Ps[wave];
      float4v s[4];
      __builtin_amdgcn_s_setprio(1);
#pragma unroll
      for (int ni = 0; ni < 4; ni++) {
        s[ni] = (float4v){0.f, 0.f, 0.f, 0.f};
        s[ni] = __builtin_amdgcn_mfma_f32_16x16x32_bf16(qf[st][0], kf[ni][0], s[ni], 0, 0, 0);
        s[ni] = __builtin_amdgcn_mfma_f32_16x16x32_bf16(qf[st][1], kf[ni][1], s[ni], 0, 0, 0);
      }
      __builtin_amdgcn_s_setprio(0);

      // row-max (raw units), 16-lane shuffle reduce
      float mt[4];
#pragma unroll
      for (int r = 0; r < 4; r++)
        mt[r] = fmaxf(fmaxf(s[0][r], s[1][r]), fmaxf(s[2][r], s[3][r]));
#pragma unroll
      for (int off = 1; off < 16; off <<= 1)
#pragma unroll
        for (int r = 0; r < 4; r++) mt[r] = fmaxf(mt[r], __shfl_xor(mt[r], off));

      // defer-max (T13, exact): only rescale when max grew past THR (log2 units)
      float g = -1e30f;
#pragma unroll
      for (int r = 0; r < 4; r++) g = fmaxf(g, mt[r] * SC - m2[st][r]);
      if (!__all(g <= 8.0f)) {
#pragma unroll
        for (int r = 0; r < 4; r++) {
          float m2n = fmaxf(m2[st][r], mt[r] * SC);
          float alpha = exp2f(m2[st][r] - m2n);
          m2[st][r] = m2n;
          l[st][r] *= alpha;
#pragma unroll
          for (int ni = 0; ni < 4; ni++) oacc[st][ni][r] *= alpha;
        }
      }

      // P = exp2(s*SC - m2); write swizzled: row*64 + ((key>>3)^(row&7))*8 + (key&7)
      float rsum[4] = {0.f, 0.f, 0.f, 0.f};
#pragma unroll
      for (int ni = 0; ni < 4; ni++)
#pragma unroll
        for (int r = 0; r < 4; r++) {
          float p = exp2f(s[ni][r] * SC - m2[st][r]);
          rsum[r] += p;
          const int prow = quad * 4 + r;
          const int gsw = (ni * 2 + (l15 >> 3)) ^ (prow & 7);
          myPs[prow * 64 + gsw * 8 + (l15 & 7)] = f32_to_bf16(p);
        }
#pragma unroll
      for (int off = 1; off < 16; off <<= 1)
#pragma unroll
        for (int r = 0; r < 4; r++) rsum[r] += __shfl_xor(rsum[r], off);
#pragma unroll
      for (int r = 0; r < 4; r++) l[st][r] += rsum[r];

      // O += P V  (pf: A[m=q][k=key]; vf: B[n=d][k=key] from Vs, swizzled)
      __builtin_amdgcn_s_setprio(1);
#pragma unroll
      for (int ks = 0; ks < 2; ks++) {
        const int gsw = (ks * 4 + quad) ^ (l15 & 7);
        short8 pf = *(const short8*)&myPs[l15 * 64 + gsw * 8];
#pragma unroll
        for (int ni = 0; ni < 4; ni++) {
          short8 vf = *(const short8*)&Vs[(ni * 16 + l15) * 64 + ((ks * 4 + quad) ^ (l15 & 7)) * 8];
          oacc[st][ni] = __builtin_amdgcn_mfma_f32_16x16x32_bf16(pf, vf, oacc[st][ni], 0, 0, 0);
        }
      }
      __builtin_amdgcn_s_setprio(0);
    }
  }

#pragma unroll
  for (int st = 0; st < 2; st++) {
    float inv[4];
#pragma unroll
    for (int r = 0; r < 4; r++) inv[r] = 1.0f / l[st][r];
#pragma unroll
    for (int ni = 0; ni < 4; ni++)
#pragma unroll
      for (int r = 0; r < 4; r++) {
        int row = b * N_ + qt * 64 + st * 32 + wave * 16 + quad * 4 + r;
        int col = h * D_ + ni * 16 + l15;
        o[(size_t)row * C_ + col] = f32_to_bf16(oacc[st][ni][r] * inv[r]);
      }
  }
}

// ---------------- launch ----------------
extern "C" void kernel_launch(void* const* d_in, const int* in_sizes, int n_in,
                              void* d_out, int out_size, void* d_ws, size_t ws_size,
                              hipStream_t stream) {
  const float* x      = (const float*)d_in[0];
  const float* ln1_w  = (const float*)d_in[1];
  const float* ln1_b  = (const float*)d_in[2];
  const float* qkv_w  = (const float*)d_in[3];
  const float* proj_w = (const float*)d_in[4];
  const float* proj_b = (const float*)d_in[5];
  const float* ln2_w  = (const float*)d_in[6];
  const float* ln2_b  = (const float*)d_in[7];
  const float* fc1_w  = (const float*)d_in[8];
  const float* fc1_b  = (const float*)d_in[9];
  const float* fc2_w  = (const float*)d_in[10];
  const float* fc2_b  = (const float*)d_in[11];
  float* out = (float*)d_out;

  char* ws = (char*)d_ws;
  size_t off = 0;
  auto alloc = [&](size_t bytes) { void* p = ws + off; off += (bytes + 255) & ~255ull; return p; };
  u16* wqkv  = (u16*)alloc((size_t)3 * C_ * C_ * 2);
  u16* wproj = (u16*)alloc((size_t)C_ * C_ * 2);
  u16* wfc1  = (u16*)alloc((size_t)HID_ * C_ * 2);
  u16* wfc2  = (u16*)alloc((size_t)C_ * HID_ * 2);
  u16* wbase = wqkv;   // contiguous (all segment sizes are 256B-multiples)
  u16* regionA = (u16*)alloc((size_t)BN_ * HID_ * 2);  // h | qkv, later o, later act
  float* xnew  = (float*)alloc((size_t)BN_ * C_ * 4);
  u16* h2      = (u16*)alloc((size_t)BN_ * C_ * 2);

  u16* hbuf = regionA;                        // [BN, C]   (dead after QKV)
  u16* qkvb = regionA + (size_t)BN_ * C_;     // [BN, 3C]  (dead after attn)
  u16* obuf = regionA;                        // [BN, C]   overwrites hbuf
  u16* act  = regionA;                        // [BN, HID] overwrites qkv+o
  u16* vtbuf = (u16*)xnew;                    // [B*H, D, N] aliases xnew (dead before proj writes)

  cast4_kernel<<<dim3(NW3_ / 256), 256, 0, stream>>>(qkv_w, proj_w, fc1_w, fc2_w, wbase);

  ln_kernel<<<dim3(BN_ / 4), 256, 0, stream>>>(x, ln1_w, ln1_b, hbuf);

  gemm_qkv<<<dim3(3 * C_ / 128, BN_ / 128), 256, 0, stream>>>(hbuf, wqkv, 3 * C_, C_, qkvb);

  transpose_v<<<dim3(N_ / 64, B_ * H_), 256, 0, stream>>>(qkvb, vtbuf);

  attn_kernel<<<dim3((N_ / 64) * B_ * H_), 128, 0, stream>>>(qkvb, vtbuf, obuf);

  gemm_proj2x<<<dim3(C_ / 128, BN_ / 128), 256, 0, stream>>>(obuf, wproj, C_, C_, proj_b, xnew);

  ln_kernel<<<dim3(BN_ / 4), 256, 0, stream>>>(xnew, ln2_w, ln2_b, h2);

  gemm_fc1gelu<<<dim3(HID_ / 128, BN_ / 128), 256, 0, stream>>>(h2, wfc1, HID_, C_, fc1_b, act);

  gemm_fc2res<<<dim3(C_ / 128, BN_ / 128), 256, 0, stream>>>(act, wfc2, C_, HID_, fc2_b, xnew, out);
}

// Round 10
// 520.327 us; speedup vs baseline: 1.0720x; 1.0003x over previous
//
#include <hip/hip_runtime.h>

// Problem constants
#define B_   32
#define N_   512
#define C_   768
#define H_   12
#define D_   64
#define HID_ 3072
#define BN_  (B_*N_)      // 16384 rows

typedef unsigned short u16;
typedef __attribute__((ext_vector_type(8))) short  short8;   // 8 bf16 (4 VGPRs)
typedef __attribute__((ext_vector_type(4))) float  float4v;  // 4 fp32 acc
typedef __attribute__((ext_vector_type(4))) float  f4;
typedef __attribute__((ext_vector_type(4))) unsigned short ushort4v;

__device__ __forceinline__ u16 f32_to_bf16(float f) {
  unsigned u = __builtin_bit_cast(unsigned, f);
  u += 0x7fffu + ((u >> 16) & 1u);   // RNE
  return (u16)(u >> 16);
}

// exact-GELU via A&S 7.1.26 erf approx, |err| < 1.5e-7 (below bf16 ulp)
__device__ __forceinline__ float gelu_f(float x) {
  float z = fabsf(x) * 0.70710678118654752f;
  float t = __builtin_amdgcn_rcpf(1.0f + 0.3275911f * z);
  float p = t * (0.254829592f +
            t * (-0.284496736f +
            t * (1.421413741f +
            t * (-1.453152027f +
            t * 1.061405429f))));
  float e = __expf(-z * z);
  float er = 1.0f - p * e;                 // erf(z)
  er = (x < 0.0f) ? -er : er;
  return 0.5f * x * (1.0f + er);
}

// async global->LDS, 16B per lane
__device__ __forceinline__ void load_lds16(const u16* g, u16* l) {
  __builtin_amdgcn_global_load_lds(
      (const __attribute__((address_space(1))) unsigned int*)g,
      (__attribute__((address_space(3))) unsigned int*)l,
      16, 0, 0);
}

// ---------------- merged weight cast f32 -> bf16, x4 vectorized ----------------
// dst buffers contiguous; all segment boundaries are multiples of 4.
#define NW0_ (3 * C_ * C_)
#define NW1_ (NW0_ + C_ * C_)
#define NW2_ (NW1_ + HID_ * C_)
#define NW3_ (NW2_ + C_ * HID_)
__global__ __launch_bounds__(256)
void cast4_kernel(const float* __restrict__ s0, const float* __restrict__ s1,
                  const float* __restrict__ s2, const float* __restrict__ s3,
                  u16* __restrict__ dst) {
  int i = (blockIdx.x * 256 + threadIdx.x) * 4;
  const float* s; int j;
  if (i < NW0_)      { s = s0; j = i; }
  else if (i < NW1_) { s = s1; j = i - NW0_; }
  else if (i < NW2_) { s = s2; j = i - NW1_; }
  else               { s = s3; j = i - NW2_; }
  f4 v = *(const f4*)(s + j);
  ushort4v o;
#pragma unroll
  for (int e = 0; e < 4; e++) o[e] = f32_to_bf16(v[e]);
  *(ushort4v*)(dst + i) = o;
}

// ---------------- LayerNorm (row = 768 fp32) -> bf16, wave-per-row ----------------
__global__ __launch_bounds__(256)
void ln_kernel(const float* __restrict__ x, const float* __restrict__ w,
               const float* __restrict__ bias, u16* __restrict__ out) {
  const int wave = threadIdx.x >> 6, lane = threadIdx.x & 63;
  const int row  = blockIdx.x * 4 + wave;
  const float* xr = x + (size_t)row * C_;

  f4 v[3];
  float s = 0.f, q = 0.f;
#pragma unroll
  for (int j = 0; j < 3; j++) {
    v[j] = *(const f4*)(xr + j * 256 + lane * 4);
#pragma unroll
    for (int e = 0; e < 4; e++) { s += v[j][e]; q += v[j][e] * v[j][e]; }
  }
#pragma unroll
  for (int off = 1; off < 64; off <<= 1) {
    s += __shfl_xor(s, off);
    q += __shfl_xor(q, off);
  }
  const float mean = s * (1.0f / C_);
  const float var  = q * (1.0f / C_) - mean * mean;
  const float rstd = rsqrtf(var + 1e-5f);

  u16* orow = out + (size_t)row * C_;
#pragma unroll
  for (int j = 0; j < 3; j++) {
    const int c = j * 256 + lane * 4;
    f4 wv = *(const f4*)(w + c);
    f4 bv = *(const f4*)(bias + c);
    ushort4v o;
#pragma unroll
    for (int e = 0; e < 4; e++)
      o[e] = f32_to_bf16((v[j][e] - mean) * rstd * wv[e] + bv[e]);
    *(ushort4v*)(orow + c) = o;   // 8B store
  }
}

// ------- V transpose: qkv unified [BN, 3C] V-cols -> Vt[B*H, D, N] --------------
__global__ __launch_bounds__(256)
void transpose_v(const u16* __restrict__ qkv, u16* __restrict__ vt) {
  __shared__ alignas(16) u16 T[64 * 72];
  const int nt = blockIdx.x, bh = blockIdx.y;
  const int b = bh / H_, h = bh % H_;
  const int tid = threadIdx.x;
  const size_t rs3 = 3 * C_;
  const int r = tid >> 2, dc = (tid & 3) * 16;
  const u16* src = qkv + (size_t)(b * N_ + nt * 64 + r) * rs3 + 2 * C_ + h * D_ + dc;
  short8 a0 = *(const short8*)src;
  short8 a1 = *(const short8*)(src + 8);
#pragma unroll
  for (int j = 0; j < 8; j++) T[(dc + j) * 72 + r] = (u16)a0[j];
#pragma unroll
  for (int j = 0; j < 8; j++) T[(dc + 8 + j) * 72 + r] = (u16)a1[j];
  __syncthreads();
  const int d = tid >> 2, nc = (tid & 3) * 16;
  u16* dst = vt + ((size_t)(b * H_ + h) * D_ + d) * N_ + nt * 64 + nc;
  *(short8*)dst       = *(const short8*)&T[d * 72 + nc];
  *(short8*)(dst + 8) = *(const short8*)&T[d * 72 + nc + 8];
}

// ================= 128x128x(BK=64) bf16 NT GEMM (proven core) ====================
template <int EPI>
__device__ __forceinline__ void gemm_core128(const u16* __restrict__ A, const u16* __restrict__ W,
                                             int N, int K,
                                             const float* __restrict__ bias,
                                             const float* __restrict__ resid,
                                             u16* __restrict__ out_bf, float* __restrict__ out_f) {
  __shared__ alignas(16) u16 As[128 * 64];
  __shared__ alignas(16) u16 Ws[128 * 64];
  const int tid  = threadIdx.x;
  const int wave = tid >> 6;
  const int lane = tid & 63;
  const int quad = lane >> 4;
  const int l15  = lane & 15;

  const int nx    = gridDim.x;
  const int lin   = blockIdx.y * nx + blockIdx.x;
  const int total = nx * gridDim.y;
  const int v     = (lin & 7) * (total >> 3) + (lin >> 3);
  const int m0 = (v / nx) << 7;
  const int n0 = (v % nx) << 7;

  const int wm = (wave >> 1) * 64;
  const int wn = (wave & 1) * 64;

  float4v acc[4][4];
#pragma unroll
  for (int i = 0; i < 4; i++)
#pragma unroll
    for (int j = 0; j < 4; j++) acc[i][j] = (float4v){0.f, 0.f, 0.f, 0.f};

  const int c0   = wave * 4;
  const int srow = lane >> 3;
  const int gcol = ((lane & 7) ^ srow) * 8;
  const u16* Ag[4];
  const u16* Wg[4];
#pragma unroll
  for (int j = 0; j < 4; j++) {
    const int row = (c0 + j) * 8 + srow;
    Ag[j] = A + (size_t)(m0 + row) * K + gcol;
    Wg[j] = W + (size_t)(n0 + row) * K + gcol;
  }

  for (int k0 = 0; k0 < K; k0 += 64) {
    __syncthreads();
#pragma unroll
    for (int j = 0; j < 4; j++) load_lds16(Ag[j] + k0, &As[(c0 + j) * 512]);
#pragma unroll
    for (int j = 0; j < 4; j++) load_lds16(Wg[j] + k0, &Ws[(c0 + j) * 512]);
    __syncthreads();

    short8 af[4][2], bf[4][2];
#pragma unroll
    for (int mi = 0; mi < 4; mi++)
#pragma unroll
      for (int ks = 0; ks < 2; ks++) {
        const int swz = ((ks * 4 + quad) ^ (l15 & 7)) * 8;
        af[mi][ks] = *(const short8*)&As[(wm + mi * 16 + l15) * 64 + swz];
        bf[mi][ks] = *(const short8*)&Ws[(wn + mi * 16 + l15) * 64 + swz];
      }
#pragma unroll
    for (int ks = 0; ks < 2; ks++)
#pragma unroll
      for (int mi = 0; mi < 4; mi++)
#pragma unroll
        for (int ni = 0; ni < 4; ni++)
          acc[mi][ni] = __builtin_amdgcn_mfma_f32_16x16x32_bf16(af[mi][ks], bf[ni][ks], acc[mi][ni], 0, 0, 0);
  }

#pragma unroll
  for (int mi = 0; mi < 4; mi++) {
#pragma unroll
    for (int r = 0; r < 4; r++) {
      const int row = m0 + wm + mi * 16 + quad * 4 + r;
#pragma unroll
      for (int ni = 0; ni < 4; ni++) {
        const int col = n0 + wn + ni * 16 + l15;
        float v2 = acc[mi][ni][r];
        if (EPI == 0) {
          out_bf[(size_t)row * N + col] = f32_to_bf16(v2);
        } else if (EPI == 1) {
          out_bf[(size_t)row * N + col] = f32_to_bf16(gelu_f(v2 + bias[col]));
        } else if (EPI == 2) {
          out_f[(size_t)row * N + col] = 2.0f * (v2 + bias[col]);
        } else {
          out_f[(size_t)row * N + col] = v2 + bias[col] + resid[(size_t)row * N + col];
        }
      }
    }
  }
}

__global__ __launch_bounds__(256, 3)
void gemm_qkv(const u16* __restrict__ A, const u16* __restrict__ W, int N, int K,
              u16* __restrict__ out_bf) {
  gemm_core128<0>(A, W, N, K, nullptr, nullptr, out_bf, nullptr);
}
__global__ __launch_bounds__(256, 3)
void gemm_proj2x(const u16* __restrict__ A, const u16* __restrict__ W, int N, int K,
                 const float* __restrict__ bias, float* __restrict__ out_f) {
  gemm_core128<2>(A, W, N, K, bias, nullptr, nullptr, out_f);
}
__global__ __launch_bounds__(256, 3)
void gemm_fc1gelu(const u16* __restrict__ A, const u16* __restrict__ W, int N, int K,
                  const float* __restrict__ bias, u16* __restrict__ out_bf) {
  gemm_core128<1>(A, W, N, K, bias, nullptr, out_bf, nullptr);
}
__global__ __launch_bounds__(256, 3)
void gemm_fc2res(const u16* __restrict__ A, const u16* __restrict__ W, int N, int K,
                 const float* __restrict__ bias, const float* __restrict__ resid,
                 float* __restrict__ out_f) {
  gemm_core128<3>(A, W, N, K, bias, resid, nullptr, out_f);
}

// ---------------- flash attention (r5-proven structure, 103us) --------------------
// 4-wave blocks, 128 q-rows, 32 KB LDS, single-buffer 2-barrier loop.  Probe ledger:
// direct-L2 KV (160us, uncoalesced gather), +dbuf (123us, 48KB LDS -> 3 blk/CU),
// 2-wave blocks (124us, 2x staging work) -- r5 structure is the local optimum.
// Numerics (refcheck'd 3x, drop-in): log2-domain softmax, exact defer-max, setprio.
__global__ __launch_bounds__(256)
void attn_kernel(const u16* __restrict__ qkv, const u16* __restrict__ vt,
                 u16* __restrict__ o) {
  __shared__ alignas(16) u16 Ks[64 * 64];
  __shared__ alignas(16) u16 Vs[64 * 64];
  __shared__ alignas(16) u16 Ps[8][16 * 64];
  const int tid  = threadIdx.x;
  const int wave = tid >> 6, lane = tid & 63;
  const int quad = lane >> 4, l15 = lane & 15;
  const int lin = blockIdx.x;
  const int bh = lin % 384, qt = lin / 384;
  const int b = bh / H_, h = bh % H_;
  const size_t rs3 = 3 * C_;
  const float SC = 0.125f * 1.44269504088896f;   // 0.125 * log2(e)

  // Q fragments from global (A-layout: m=lane&15, k=quad*8+j), 2 strips
  short8 qf[2][2];
#pragma unroll
  for (int st = 0; st < 2; st++) {
    const int qrow = b * N_ + qt * 128 + st * 64 + wave * 16 + l15;
    const u16* qp = qkv + (size_t)qrow * rs3 + h * D_ + quad * 8;
    qf[st][0] = *(const short8*)qp;
    qf[st][1] = *(const short8*)(qp + 32);
  }

  // staging sources (8 chunks of 8 rows; wave stages chunks 2w, 2w+1)
  const int srow = lane >> 3;
  const int gcol = ((lane & 7) ^ srow) * 8;
  const int ch0 = wave * 2, ch1 = wave * 2 + 1;
  const u16* kg0 = qkv + (size_t)(b * N_ + ch0 * 8 + srow) * rs3 + C_ + h * D_ + gcol;
  const u16* kg1 = qkv + (size_t)(b * N_ + ch1 * 8 + srow) * rs3 + C_ + h * D_ + gcol;
  const u16* vg0 = vt + ((size_t)bh * D_ + ch0 * 8 + srow) * N_ + gcol;
  const u16* vg1 = vt + ((size_t)bh * D_ + ch1 * 8 + srow) * N_ + gcol;

  float m2[2][4], l[2][4];
  float4v oacc[2][4];
#pragma unroll
  for (int st = 0; st < 2; st++)
#pragma unroll
    for (int r = 0; r < 4; r++) { m2[st][r] = -1e30f; l[st][r] = 0.f; }
#pragma unroll
  for (int st = 0; st < 2; st++)
#pragma unroll
    for (int ni = 0; ni < 4; ni++) oacc[st][ni] = (float4v){0.f, 0.f, 0.f, 0.f};

  for (int kt = 0; kt < 8; ++kt) {
    __syncthreads();
    load_lds16(kg0 + (size_t)(kt * 64) * rs3, &Ks[ch0 * 512]);
    load_lds16(kg1 + (size_t)(kt * 64) * rs3, &Ks[ch1 * 512]);
    load_lds16(vg0 + kt * 64, &Vs[ch0 * 512]);
    load_lds16(vg1 + kt * 64, &Vs[ch1 * 512]);
    __syncthreads();

    // K fragments (B[n=key][k=d]) shared by both strips
    short8 kf[4][2];
#pragma unroll
    for (int ni = 0; ni < 4; ni++)
#pragma unroll
      for (int ks = 0; ks < 2; ks++)
        kf[ni][ks] = *(const short8*)&Ks[(ni * 16 + l15) * 64 + ((ks * 4 + quad) ^ (l15 & 7)) * 8];

#pragma unroll
    for (int st = 0; st < 2; st++) {
      u16* myPs = Ps[wave * 2 + st];
      float4v s[4];
      __builtin_amdgcn_s_setprio(1);
#pragma unroll
      for (int ni = 0; ni < 4; ni++) {
        s[ni] = (float4v){0.f, 0.f, 0.f, 0.f};
        s[ni] = __builtin_amdgcn_mfma_f32_16x16x32_bf16(qf[st][0], kf[ni][0], s[ni], 0, 0, 0);
        s[ni] = __builtin_amdgcn_mfma_f32_16x16x32_bf16(qf[st][1], kf[ni][1], s[ni], 0, 0, 0);
      }
      __builtin_amdgcn_s_setprio(0);

      // row-max (raw units), 16-lane shuffle reduce
      float mt[4];
#pragma unroll
      for (int r = 0; r < 4; r++)
        mt[r] = fmaxf(fmaxf(s[0][r], s[1][r]), fmaxf(s[2][r], s[3][r]));
#pragma unroll
      for (int off = 1; off < 16; off <<= 1)
#pragma unroll
        for (int r = 0; r < 4; r++) mt[r] = fmaxf(mt[r], __shfl_xor(mt[r], off));

      // defer-max (T13, exact): only rescale when max grew past THR (log2 units)
      float g = -1e30f;
#pragma unroll
      for (int r = 0; r < 4; r++) g = fmaxf(g, mt[r] * SC - m2[st][r]);
      if (!__all(g <= 8.0f)) {
#pragma unroll
        for (int r = 0; r < 4; r++) {
          float m2n = fmaxf(m2[st][r], mt[r] * SC);
          float alpha = exp2f(m2[st][r] - m2n);
          m2[st][r] = m2n;
          l[st][r] *= alpha;
#pragma unroll
          for (int ni = 0; ni < 4; ni++) oacc[st][ni][r] *= alpha;
        }
      }

      // P = exp2(s*SC - m2); write swizzled: row*64 + ((key>>3)^(row&7))*8 + (key&7)
      float rsum[4] = {0.f, 0.f, 0.f, 0.f};
#pragma unroll
      for (int ni = 0; ni < 4; ni++)
#pragma unroll
        for (int r = 0; r < 4; r++) {
          float p = exp2f(s[ni][r] * SC - m2[st][r]);
          rsum[r] += p;
          const int prow = quad * 4 + r;
          const int gsw = (ni * 2 + (l15 >> 3)) ^ (prow & 7);
          myPs[prow * 64 + gsw * 8 + (l15 & 7)] = f32_to_bf16(p);
        }
#pragma unroll
      for (int off = 1; off < 16; off <<= 1)
#pragma unroll
        for (int r = 0; r < 4; r++) rsum[r] += __shfl_xor(rsum[r], off);
#pragma unroll
      for (int r = 0; r < 4; r++) l[st][r] += rsum[r];

      // O += P V  (pf: A[m=q][k=key]; vf: B[n=d][k=key] from Vs, swizzled)
      __builtin_amdgcn_s_setprio(1);
#pragma unroll
      for (int ks = 0; ks < 2; ks++) {
        const int gsw = (ks * 4 + quad) ^ (l15 & 7);
        short8 pf = *(const short8*)&myPs[l15 * 64 + gsw * 8];
#pragma unroll
        for (int ni = 0; ni < 4; ni++) {
          short8 vf = *(const short8*)&Vs[(ni * 16 + l15) * 64 + ((ks * 4 + quad) ^ (l15 & 7)) * 8];
          oacc[st][ni] = __builtin_amdgcn_mfma_f32_16x16x32_bf16(pf, vf, oacc[st][ni], 0, 0, 0);
        }
      }
      __builtin_amdgcn_s_setprio(0);
    }
  }

#pragma unroll
  for (int st = 0; st < 2; st++) {
    float inv[4];
#pragma unroll
    for (int r = 0; r < 4; r++) inv[r] = 1.0f / l[st][r];
#pragma unroll
    for (int ni = 0; ni < 4; ni++)
#pragma unroll
      for (int r = 0; r < 4; r++) {
        int row = b * N_ + qt * 128 + st * 64 + wave * 16 + quad * 4 + r;
        int col = h * D_ + ni * 16 + l15;
        o[(size_t)row * C_ + col] = f32_to_bf16(oacc[st][ni][r] * inv[r]);
      }
  }
}

// ---------------- launch ----------------
extern "C" void kernel_launch(void* const* d_in, const int* in_sizes, int n_in,
                              void* d_out, int out_size, void* d_ws, size_t ws_size,
                              hipStream_t stream) {
  const float* x      = (const float*)d_in[0];
  const float* ln1_w  = (const float*)d_in[1];
  const float* ln1_b  = (const float*)d_in[2];
  const float* qkv_w  = (const float*)d_in[3];
  const float* proj_w = (const float*)d_in[4];
  const float* proj_b = (const float*)d_in[5];
  const float* ln2_w  = (const float*)d_in[6];
  const float* ln2_b  = (const float*)d_in[7];
  const float* fc1_w  = (const float*)d_in[8];
  const float* fc1_b  = (const float*)d_in[9];
  const float* fc2_w  = (const float*)d_in[10];
  const float* fc2_b  = (const float*)d_in[11];
  float* out = (float*)d_out;

  char* ws = (char*)d_ws;
  size_t off = 0;
  auto alloc = [&](size_t bytes) { void* p = ws + off; off += (bytes + 255) & ~255ull; return p; };
  u16* wqkv  = (u16*)alloc((size_t)3 * C_ * C_ * 2);
  u16* wproj = (u16*)alloc((size_t)C_ * C_ * 2);
  u16* wfc1  = (u16*)alloc((size_t)HID_ * C_ * 2);
  u16* wfc2  = (u16*)alloc((size_t)C_ * HID_ * 2);
  u16* wbase = wqkv;   // contiguous (all segment sizes are 256B-multiples)
  u16* regionA = (u16*)alloc((size_t)BN_ * HID_ * 2);  // h | qkv, later o, later act
  float* xnew  = (float*)alloc((size_t)BN_ * C_ * 4);
  u16* h2      = (u16*)alloc((size_t)BN_ * C_ * 2);

  u16* hbuf = regionA;                        // [BN, C]   (dead after QKV)
  u16* qkvb = regionA + (size_t)BN_ * C_;     // [BN, 3C]  (dead after attn)
  u16* obuf = regionA;                        // [BN, C]   overwrites hbuf
  u16* act  = regionA;                        // [BN, HID] overwrites qkv+o
  u16* vtbuf = (u16*)xnew;                    // [B*H, D, N] aliases xnew (dead before proj writes)

  cast4_kernel<<<dim3(NW3_ / 1024), 256, 0, stream>>>(qkv_w, proj_w, fc1_w, fc2_w, wbase);

  ln_kernel<<<dim3(BN_ / 4), 256, 0, stream>>>(x, ln1_w, ln1_b, hbuf);

  gemm_qkv<<<dim3(3 * C_ / 128, BN_ / 128), 256, 0, stream>>>(hbuf, wqkv, 3 * C_, C_, qkvb);

  transpose_v<<<dim3(N_ / 64, B_ * H_), 256, 0, stream>>>(qkvb, vtbuf);

  attn_kernel<<<dim3((N_ / 128) * B_ * H_), 256, 0, stream>>>(qkvb, vtbuf, obuf);

  gemm_proj2x<<<dim3(C_ / 128, BN_ / 128), 256, 0, stream>>>(obuf, wproj, C_, C_, proj_b, xnew);

  ln_kernel<<<dim3(BN_ / 4), 256, 0, stream>>>(xnew, ln2_w, ln2_b, h2);

  gemm_fc1gelu<<<dim3(HID_ / 128, BN_ / 128), 256, 0, stream>>>(h2, wfc1, HID_, C_, fc1_b, act);

  gemm_fc2res<<<dim3(C_ / 128, BN_ / 128), 256, 0, stream>>>(act, wfc2, C_, HID_, fc2_b, xnew, out);
}